// Round 1
// baseline (1060.796 us; speedup 1.0000x reference)
//
#include <hip/hip_runtime.h>
#include <math.h>

#define NEG_SLOPE 0.2f

// ---------------- node transform for conv1: h1 = x@W1, a_src1, a_dst1 ----------------
__global__ void k_node1(const float* __restrict__ x, const float* __restrict__ W1,
                        const float* __restrict__ as1, const float* __restrict__ ad1,
                        float* __restrict__ h1, float* __restrict__ a_src1,
                        float* __restrict__ a_dst1, int N) {
    int n = blockIdx.x * blockDim.x + threadIdx.x;
    if (n >= N) return;
    float xv[8];
#pragma unroll
    for (int k = 0; k < 8; k++) xv[k] = x[n * 8 + k];
    float h[32];
#pragma unroll
    for (int j = 0; j < 32; j++) {
        float acc = 0.f;
#pragma unroll
        for (int k = 0; k < 8; k++) acc += xv[k] * W1[k * 32 + j];
        h[j] = acc;
        h1[n * 32 + j] = acc;
    }
#pragma unroll
    for (int hh = 0; hh < 2; hh++) {
        float s = 0.f, d = 0.f;
#pragma unroll
        for (int c = 0; c < 16; c++) {
            s += h[hh * 16 + c] * as1[hh * 16 + c];
            d += h[hh * 16 + c] * ad1[hh * 16 + c];
        }
        a_src1[n * 2 + hh] = s;
        a_dst1[n * 2 + hh] = d;
    }
}

// ---------------- CSR build ----------------
__global__ void k_deg_init(int* __restrict__ deg, int N) {
    int n = blockIdx.x * blockDim.x + threadIdx.x;
    if (n < N) deg[n] = 1;  // self-loop
}

__global__ void k_deg_count(const int* __restrict__ ei, int* __restrict__ deg, int E) {
    int e = blockIdx.x * blockDim.x + threadIdx.x;
    if (e < E) atomicAdd(&deg[ei[E + e]], 1);  // dst
}

__global__ void k_scan(const int* __restrict__ deg, int* __restrict__ rowptr,
                       int* __restrict__ cursor, int N) {
    int lane = threadIdx.x;  // blockDim = 64, grid = 1
    int chunk = (N + 63) >> 6;
    int beg = lane * chunk;
    int end = beg + chunk; if (end > N) end = N;
    int s = 0;
    for (int i = beg; i < end && i >= 0; i++) s += deg[i];
    int incl = s;
#pragma unroll
    for (int off = 1; off < 64; off <<= 1) {
        int v = __shfl_up(incl, off);
        if (lane >= off) incl += v;
    }
    int run = incl - s;  // exclusive prefix
    for (int i = beg; i < end; i++) {
        rowptr[i] = run;
        cursor[i] = run;
        run += deg[i];
    }
    if (end == N) rowptr[N] = run;  // total
}

__global__ void k_scatter(const int* __restrict__ ei, int* __restrict__ cursor,
                          int* __restrict__ adj, int E, int N) {
    int i = blockIdx.x * blockDim.x + threadIdx.x;
    if (i >= E + N) return;
    int s, d;
    if (i < E) { s = ei[i]; d = ei[E + i]; }
    else { s = i - E; d = i - E; }      // self-loop
    int pos = atomicAdd(&cursor[d], 1);
    adj[pos] = s;
}

// ---------------- conv1 aggregate: 2 nodes per wave (32 channels each) ----------------
__global__ void k_conv1(const int* __restrict__ rowptr, const int* __restrict__ adj,
                        const float* __restrict__ a_src, const float* __restrict__ a_dst,
                        const float* __restrict__ h1, const float* __restrict__ b1,
                        float* __restrict__ out1, int N) {
    int lane = threadIdx.x & 63;
    int wave = (blockIdx.x * blockDim.x + threadIdx.x) >> 6;
    int slot = lane >> 5;
    int c32 = lane & 31;
    int hh = c32 >> 4;
    int n = wave * 2 + slot;
    if (n >= N) return;
    int beg = rowptr[n], end = rowptr[n + 1];
    float ad = a_dst[n * 2 + hh];
    float m = -1e30f;
    for (int j = beg; j < end; j++) {
        int s = adj[j];
        float t = a_src[s * 2 + hh] + ad;
        t = t > 0.f ? t : NEG_SLOPE * t;
        m = fmaxf(m, t);
    }
    float denom = 0.f, acc = 0.f;
    for (int j = beg; j < end; j++) {
        int s = adj[j];
        float t = a_src[s * 2 + hh] + ad;
        t = t > 0.f ? t : NEG_SLOPE * t;
        float ex = __expf(t - m);
        denom += ex;
        acc += ex * h1[s * 32 + c32];
    }
    out1[n * 32 + c32] = fmaxf(acc / denom + b1[c32], 0.f);
}

// ---------------- node transform for conv2: h2 = out1@W2, a_src2, a_dst2 ----------------
__global__ void k_node2(const float* __restrict__ out1, const float* __restrict__ W2,
                        const float* __restrict__ as2, const float* __restrict__ ad2,
                        float* __restrict__ h2, float* __restrict__ a_src2,
                        float* __restrict__ a_dst2, int N) {
    int lane = threadIdx.x & 63;
    int n = (blockIdx.x * blockDim.x + threadIdx.x) >> 6;
    if (n >= N) return;
    float acc = 0.f;
#pragma unroll
    for (int k = 0; k < 32; k++) acc += out1[n * 32 + k] * W2[k * 64 + lane];
    h2[n * 64 + lane] = acc;
    float s = acc * as2[lane];
    float d = acc * ad2[lane];
#pragma unroll
    for (int off = 16; off >= 1; off >>= 1) {
        s += __shfl_xor(s, off);
        d += __shfl_xor(d, off);
    }
    if ((lane & 31) == 0) {
        a_src2[n * 2 + (lane >> 5)] = s;
        a_dst2[n * 2 + (lane >> 5)] = d;
    }
}

// ---------------- conv2 aggregate: 1 node per wave (64 channels) ----------------
__global__ void k_conv2(const int* __restrict__ rowptr, const int* __restrict__ adj,
                        const float* __restrict__ a_src, const float* __restrict__ a_dst,
                        const float* __restrict__ h2, const float* __restrict__ b2,
                        float* __restrict__ hfin, int N) {
    int lane = threadIdx.x & 63;
    int n = (blockIdx.x * blockDim.x + threadIdx.x) >> 6;
    if (n >= N) return;
    int hh = lane >> 5;
    int beg = rowptr[n], end = rowptr[n + 1];
    float ad = a_dst[n * 2 + hh];
    float m = -1e30f;
    for (int j = beg; j < end; j++) {
        int s = adj[j];
        float t = a_src[s * 2 + hh] + ad;
        t = t > 0.f ? t : NEG_SLOPE * t;
        m = fmaxf(m, t);
    }
    float denom = 0.f, acc = 0.f;
    for (int j = beg; j < end; j++) {
        int s = adj[j];
        float t = a_src[s * 2 + hh] + ad;
        t = t > 0.f ? t : NEG_SLOPE * t;
        float ex = __expf(t - m);
        denom += ex;
        acc += ex * h2[s * 64 + lane];
    }
    hfin[n * 64 + lane] = fmaxf(acc / denom + b2[lane], 0.f);
}

// ---------------- edge head: out = relu((h[r]+h[c])@fc1 + b)@fc2 + b2 ----------------
__global__ void k_head(const int* __restrict__ ei, const float* __restrict__ hfin,
                       const float* __restrict__ w1, const float* __restrict__ b1,
                       const float* __restrict__ w2, const float* __restrict__ b2,
                       float* __restrict__ out, int E) {
    int e = blockIdx.x * blockDim.x + threadIdx.x;
    if (e >= E) return;
    int r = ei[e], c = ei[E + e];
    const float4* hr = (const float4*)(hfin + (size_t)r * 64);
    const float4* hc = (const float4*)(hfin + (size_t)c * 64);
    float ev[64];
#pragma unroll
    for (int t = 0; t < 16; t++) {
        float4 a = hr[t], b = hc[t];
        ev[4 * t + 0] = a.x + b.x;
        ev[4 * t + 1] = a.y + b.y;
        ev[4 * t + 2] = a.z + b.z;
        ev[4 * t + 3] = a.w + b.w;
    }
    float o = b2[0];
    for (int j = 0; j < 64; j++) {
        float acc = b1[j];
#pragma unroll
        for (int k = 0; k < 64; k++) acc += ev[k] * w1[k * 64 + j];
        o += fmaxf(acc, 0.f) * w2[j];
    }
    out[e] = o;
}

extern "C" void kernel_launch(void* const* d_in, const int* in_sizes, int n_in,
                              void* d_out, int out_size, void* d_ws, size_t ws_size,
                              hipStream_t stream) {
    const float* x   = (const float*)d_in[0];
    const int*   ei  = (const int*)d_in[1];
    const float* W1  = (const float*)d_in[2];
    const float* as1 = (const float*)d_in[3];
    const float* ad1 = (const float*)d_in[4];
    const float* b1  = (const float*)d_in[5];
    const float* W2  = (const float*)d_in[6];
    const float* as2 = (const float*)d_in[7];
    const float* ad2 = (const float*)d_in[8];
    const float* b2  = (const float*)d_in[9];
    const float* fw1 = (const float*)d_in[10];
    const float* fb1 = (const float*)d_in[11];
    const float* fw2 = (const float*)d_in[12];
    const float* fb2 = (const float*)d_in[13];
    float* out = (float*)d_out;

    int N = in_sizes[0] / 8;
    int E = in_sizes[1] / 2;

    // workspace layout (floats / ints)
    char* w = (char*)d_ws;
    float* h1    = (float*)w;              w += (size_t)N * 32 * 4;
    float* asr1  = (float*)w;              w += (size_t)N * 2 * 4;
    float* adt1  = (float*)w;              w += (size_t)N * 2 * 4;
    float* out1  = (float*)w;              w += (size_t)N * 32 * 4;
    float* h2    = (float*)w;              w += (size_t)N * 64 * 4;
    float* asr2  = (float*)w;              w += (size_t)N * 2 * 4;
    float* adt2  = (float*)w;              w += (size_t)N * 2 * 4;
    float* hfin  = (float*)w;              w += (size_t)N * 64 * 4;
    int*   deg   = (int*)w;                w += (size_t)N * 4;
    int*   rowp  = (int*)w;                w += (size_t)(N + 1) * 4;
    int*   curs  = (int*)w;                w += (size_t)N * 4;
    int*   adj   = (int*)w;                w += (size_t)(E + N) * 4;

    int B = 256;
    // node transform 1
    k_node1<<<(N + B - 1) / B, B, 0, stream>>>(x, W1, as1, ad1, h1, asr1, adt1, N);
    // CSR build
    k_deg_init<<<(N + B - 1) / B, B, 0, stream>>>(deg, N);
    k_deg_count<<<(E + B - 1) / B, B, 0, stream>>>(ei, deg, E);
    k_scan<<<1, 64, 0, stream>>>(deg, rowp, curs, N);
    k_scatter<<<(E + N + B - 1) / B, B, 0, stream>>>(ei, curs, adj, E, N);
    // conv1 aggregate (2 nodes per wave)
    {
        long long waves = (N + 1) / 2;
        long long thr = waves * 64;
        k_conv1<<<(int)((thr + B - 1) / B), B, 0, stream>>>(rowp, adj, asr1, adt1, h1, b1, out1, N);
    }
    // node transform 2 (1 node per wave)
    {
        long long thr = (long long)N * 64;
        k_node2<<<(int)((thr + B - 1) / B), B, 0, stream>>>(out1, W2, as2, ad2, h2, asr2, adt2, N);
    }
    // conv2 aggregate (1 node per wave)
    {
        long long thr = (long long)N * 64;
        k_conv2<<<(int)((thr + B - 1) / B), B, 0, stream>>>(rowp, adj, asr2, adt2, h2, b2, hfin, N);
    }
    // edge head
    k_head<<<(E + B - 1) / B, B, 0, stream>>>(ei, hfin, fw1, fb1, fw2, fb2, out, E);
}

// Round 2
// 715.410 us; speedup vs baseline: 1.4828x; 1.4828x over previous
//
#include <hip/hip_runtime.h>
#include <math.h>

#define NEG_SLOPE 0.2f

// ---------------- node transform for conv1: h1 = x@W1, a_src1, a_dst1 ----------------
__global__ void k_node1(const float* __restrict__ x, const float* __restrict__ W1,
                        const float* __restrict__ as1, const float* __restrict__ ad1,
                        float* __restrict__ h1, float* __restrict__ a_src1,
                        float* __restrict__ a_dst1, int N) {
    int n = blockIdx.x * blockDim.x + threadIdx.x;
    if (n >= N) return;
    float xv[8];
#pragma unroll
    for (int k = 0; k < 8; k++) xv[k] = x[n * 8 + k];
    float h[32];
#pragma unroll
    for (int j = 0; j < 32; j++) {
        float acc = 0.f;
#pragma unroll
        for (int k = 0; k < 8; k++) acc += xv[k] * W1[k * 32 + j];
        h[j] = acc;
        h1[n * 32 + j] = acc;
    }
#pragma unroll
    for (int hh = 0; hh < 2; hh++) {
        float s = 0.f, d = 0.f;
#pragma unroll
        for (int c = 0; c < 16; c++) {
            s += h[hh * 16 + c] * as1[hh * 16 + c];
            d += h[hh * 16 + c] * ad1[hh * 16 + c];
        }
        a_src1[n * 2 + hh] = s;
        a_dst1[n * 2 + hh] = d;
    }
}

// ---------------- CSR build ----------------
__global__ void k_deg_init(int* __restrict__ deg, int* __restrict__ rowptr, int N, int E) {
    int n = blockIdx.x * blockDim.x + threadIdx.x;
    if (n < N) deg[n] = 1;  // self-loop
    if (n == 0) rowptr[N] = E + N;
}

__global__ void k_deg_count(const int* __restrict__ ei, int* __restrict__ deg, int E) {
    int e = blockIdx.x * blockDim.x + threadIdx.x;
    if (e < E) atomicAdd(&deg[ei[E + e]], 1);  // dst
}

// 1024-thread single-block hierarchical scan
__global__ void k_scan(const int* __restrict__ deg, int* __restrict__ rowptr,
                       int* __restrict__ cursor, int N) {
    __shared__ int wsum[16];
    __shared__ int wpre[16];
    int tid = threadIdx.x;
    int lane = tid & 63, wid = tid >> 6;
    int chunk = (N + 1023) >> 10;
    int beg = tid * chunk;
    int end = beg + chunk; if (end > N) end = N;
    int s = 0;
    for (int i = beg; i < end; i++) s += deg[i];
    int incl = s;
#pragma unroll
    for (int off = 1; off < 64; off <<= 1) {
        int v = __shfl_up(incl, off);
        if (lane >= off) incl += v;
    }
    if (lane == 63) wsum[wid] = incl;
    __syncthreads();
    if (tid == 0) {
        int r = 0;
        for (int i = 0; i < 16; i++) { wpre[i] = r; r += wsum[i]; }
    }
    __syncthreads();
    int run = wpre[wid] + incl - s;  // exclusive prefix over all
    for (int i = beg; i < end; i++) {
        rowptr[i] = run;
        cursor[i] = run;
        run += deg[i];
    }
}

__global__ void k_scatter(const int* __restrict__ ei, int* __restrict__ cursor,
                          int* __restrict__ adj, int E, int N) {
    int i = blockIdx.x * blockDim.x + threadIdx.x;
    if (i >= E + N) return;
    int s, d;
    if (i < E) { s = ei[i]; d = ei[E + i]; }
    else { s = i - E; d = i - E; }      // self-loop
    int pos = atomicAdd(&cursor[d], 1);
    adj[pos] = s;
}

// ---------------- conv1 aggregate: 2 nodes per wave, single-pass online softmax ----------------
__global__ void k_conv1(const int* __restrict__ rowptr, const int* __restrict__ adj,
                        const float* __restrict__ a_src, const float* __restrict__ a_dst,
                        const float* __restrict__ h1, const float* __restrict__ b1,
                        float* __restrict__ out1, int N) {
    int lane = threadIdx.x & 63;
    int wave = (blockIdx.x * blockDim.x + threadIdx.x) >> 6;
    int sub = lane & 31;           // channel 0..31
    int slot = lane >> 5;
    int hh = sub >> 4;
    int n = wave * 2 + slot;
    if (n >= N) return;
    int beg = rowptr[n], end = rowptr[n + 1];
    float ad = a_dst[n * 2 + hh];
    float m = -1e30f, denom = 0.f, acc = 0.f;
    for (int j0 = beg; j0 < end; j0 += 32) {
        int idx = j0 + sub;
        int av = (idx < end) ? adj[idx] : 0;
        int cnt = end - j0; if (cnt > 32) cnt = 32;
        for (int jj = 0; jj < cnt; jj++) {
            int s = __shfl(av, jj, 32);
            float t = a_src[s * 2 + hh] + ad;
            t = t > 0.f ? t : NEG_SLOPE * t;
            float mn = fmaxf(m, t);
            float scale = __expf(m - mn);
            float ex = __expf(t - mn);
            float hv = h1[s * 32 + sub];
            denom = denom * scale + ex;
            acc = acc * scale + ex * hv;
            m = mn;
        }
    }
    out1[n * 32 + sub] = fmaxf(acc / denom + b1[sub], 0.f);
}

// ---------------- node transform for conv2 ----------------
__global__ void k_node2(const float* __restrict__ out1, const float* __restrict__ W2,
                        const float* __restrict__ as2, const float* __restrict__ ad2,
                        float* __restrict__ h2, float* __restrict__ a_src2,
                        float* __restrict__ a_dst2, int N) {
    int lane = threadIdx.x & 63;
    int n = (blockIdx.x * blockDim.x + threadIdx.x) >> 6;
    if (n >= N) return;
    float acc = 0.f;
#pragma unroll
    for (int k = 0; k < 32; k++) acc += out1[n * 32 + k] * W2[k * 64 + lane];
    h2[n * 64 + lane] = acc;
    float s = acc * as2[lane];
    float d = acc * ad2[lane];
#pragma unroll
    for (int off = 16; off >= 1; off >>= 1) {
        s += __shfl_xor(s, off);
        d += __shfl_xor(d, off);
    }
    if ((lane & 31) == 0) {
        a_src2[n * 2 + (lane >> 5)] = s;
        a_dst2[n * 2 + (lane >> 5)] = d;
    }
}

// ---------------- conv2 aggregate: 1 node per wave, single-pass online softmax ----------------
__global__ void k_conv2(const int* __restrict__ rowptr, const int* __restrict__ adj,
                        const float* __restrict__ a_src, const float* __restrict__ a_dst,
                        const float* __restrict__ h2, const float* __restrict__ b2,
                        float* __restrict__ hfin, int N) {
    int lane = threadIdx.x & 63;
    int n = (blockIdx.x * blockDim.x + threadIdx.x) >> 6;
    if (n >= N) return;
    int hh = lane >> 5;
    int beg = rowptr[n], end = rowptr[n + 1];
    float ad = a_dst[n * 2 + hh];
    float m = -1e30f, denom = 0.f, acc = 0.f;
    for (int j0 = beg; j0 < end; j0 += 64) {
        int idx = j0 + lane;
        int av = (idx < end) ? adj[idx] : 0;
        int cnt = end - j0; if (cnt > 64) cnt = 64;
        for (int jj = 0; jj < cnt; jj++) {
            int s = __shfl(av, jj);
            float t = a_src[s * 2 + hh] + ad;
            t = t > 0.f ? t : NEG_SLOPE * t;
            float mn = fmaxf(m, t);
            float scale = __expf(m - mn);
            float ex = __expf(t - mn);
            float hv = h2[s * 64 + lane];
            denom = denom * scale + ex;
            acc = acc * scale + ex * hv;
            m = mn;
        }
    }
    hfin[n * 64 + lane] = fmaxf(acc / denom + b2[lane], 0.f);
}

// ---------------- edge head: out = relu((h[r]+h[c])@fc1 + b)@fc2 + b2 ----------------
// Register-resident ev[64] (launch_bounds relaxes VGPR cap); w1 accesses are
// lane-uniform -> scalar loads on the SMEM pipe, overlapping the VALU FMAs.
__global__ __launch_bounds__(256, 2) void k_head(
        const int* __restrict__ ei, const float* __restrict__ hfin,
        const float* __restrict__ w1, const float* __restrict__ b1,
        const float* __restrict__ w2, const float* __restrict__ b2,
        float* __restrict__ out, int E) {
    int e = blockIdx.x * blockDim.x + threadIdx.x;
    if (e >= E) return;
    int r = ei[e], c = ei[E + e];
    const float4* hr = (const float4*)(hfin + (size_t)r * 64);
    const float4* hc = (const float4*)(hfin + (size_t)c * 64);
    float ev[64];
#pragma unroll
    for (int t = 0; t < 16; t++) {
        float4 a = hr[t], b = hc[t];
        ev[4 * t + 0] = a.x + b.x;
        ev[4 * t + 1] = a.y + b.y;
        ev[4 * t + 2] = a.z + b.z;
        ev[4 * t + 3] = a.w + b.w;
    }
    float o = b2[0];
    for (int j0 = 0; j0 < 64; j0 += 8) {
        float acc[8];
#pragma unroll
        for (int jj = 0; jj < 8; jj++) acc[jj] = b1[j0 + jj];
#pragma unroll
        for (int k = 0; k < 64; k++) {
            float evk = ev[k];
#pragma unroll
            for (int jj = 0; jj < 8; jj++) acc[jj] += evk * w1[k * 64 + j0 + jj];
        }
#pragma unroll
        for (int jj = 0; jj < 8; jj++) o += fmaxf(acc[jj], 0.f) * w2[j0 + jj];
    }
    out[e] = o;
}

extern "C" void kernel_launch(void* const* d_in, const int* in_sizes, int n_in,
                              void* d_out, int out_size, void* d_ws, size_t ws_size,
                              hipStream_t stream) {
    const float* x   = (const float*)d_in[0];
    const int*   ei  = (const int*)d_in[1];
    const float* W1  = (const float*)d_in[2];
    const float* as1 = (const float*)d_in[3];
    const float* ad1 = (const float*)d_in[4];
    const float* b1  = (const float*)d_in[5];
    const float* W2  = (const float*)d_in[6];
    const float* as2 = (const float*)d_in[7];
    const float* ad2 = (const float*)d_in[8];
    const float* b2  = (const float*)d_in[9];
    const float* fw1 = (const float*)d_in[10];
    const float* fb1 = (const float*)d_in[11];
    const float* fw2 = (const float*)d_in[12];
    const float* fb2 = (const float*)d_in[13];
    float* out = (float*)d_out;

    int N = in_sizes[0] / 8;
    int E = in_sizes[1] / 2;

    // workspace layout
    char* w = (char*)d_ws;
    float* h1    = (float*)w;              w += (size_t)N * 32 * 4;
    float* asr1  = (float*)w;              w += (size_t)N * 2 * 4;
    float* adt1  = (float*)w;              w += (size_t)N * 2 * 4;
    float* out1  = (float*)w;              w += (size_t)N * 32 * 4;
    float* h2    = (float*)w;              w += (size_t)N * 64 * 4;
    float* asr2  = (float*)w;              w += (size_t)N * 2 * 4;
    float* adt2  = (float*)w;              w += (size_t)N * 2 * 4;
    float* hfin  = (float*)w;              w += (size_t)N * 64 * 4;
    int*   deg   = (int*)w;                w += (size_t)N * 4;
    int*   rowp  = (int*)w;                w += (size_t)(N + 1) * 4;
    int*   curs  = (int*)w;                w += (size_t)N * 4;
    int*   adj   = (int*)w;                w += (size_t)(E + N) * 4;

    int B = 256;
    k_node1<<<(N + B - 1) / B, B, 0, stream>>>(x, W1, as1, ad1, h1, asr1, adt1, N);
    k_deg_init<<<(N + B - 1) / B, B, 0, stream>>>(deg, rowp, N, E);
    k_deg_count<<<(E + B - 1) / B, B, 0, stream>>>(ei, deg, E);
    k_scan<<<1, 1024, 0, stream>>>(deg, rowp, curs, N);
    k_scatter<<<(E + N + B - 1) / B, B, 0, stream>>>(ei, curs, adj, E, N);
    {
        long long thr = (long long)((N + 1) / 2) * 64;
        k_conv1<<<(int)((thr + B - 1) / B), B, 0, stream>>>(rowp, adj, asr1, adt1, h1, b1, out1, N);
    }
    {
        long long thr = (long long)N * 64;
        k_node2<<<(int)((thr + B - 1) / B), B, 0, stream>>>(out1, W2, as2, ad2, h2, asr2, adt2, N);
    }
    {
        long long thr = (long long)N * 64;
        k_conv2<<<(int)((thr + B - 1) / B), B, 0, stream>>>(rowp, adj, asr2, adt2, h2, b2, hfin, N);
    }
    k_head<<<(E + B - 1) / B, B, 0, stream>>>(ei, hfin, fw1, fb1, fw2, fb2, out, E);
}

// Round 5
// 692.715 us; speedup vs baseline: 1.5314x; 1.0328x over previous
//
#include <hip/hip_runtime.h>
#include <math.h>

#define NEG_SLOPE 0.2f

// ---------------- node transform for conv1: h1 = x@W1, a_src1, a_dst1 ----------------
__global__ void k_node1(const float* __restrict__ x, const float* __restrict__ W1,
                        const float* __restrict__ as1, const float* __restrict__ ad1,
                        float* __restrict__ h1, float* __restrict__ a_src1,
                        float* __restrict__ a_dst1, int N) {
    int n = blockIdx.x * blockDim.x + threadIdx.x;
    if (n >= N) return;
    float xv[8];
#pragma unroll
    for (int k = 0; k < 8; k++) xv[k] = x[n * 8 + k];
    float h[32];
#pragma unroll
    for (int j = 0; j < 32; j++) {
        float acc = 0.f;
#pragma unroll
        for (int k = 0; k < 8; k++) acc += xv[k] * W1[k * 32 + j];
        h[j] = acc;
        h1[n * 32 + j] = acc;
    }
#pragma unroll
    for (int hh = 0; hh < 2; hh++) {
        float s = 0.f, d = 0.f;
#pragma unroll
        for (int c = 0; c < 16; c++) {
            s += h[hh * 16 + c] * as1[hh * 16 + c];
            d += h[hh * 16 + c] * ad1[hh * 16 + c];
        }
        a_src1[n * 2 + hh] = s;
        a_dst1[n * 2 + hh] = d;
    }
}

// ---------------- CSR build ----------------
__global__ void k_deg_init(int* __restrict__ deg, int* __restrict__ rowptr, int N, int E) {
    int n = blockIdx.x * blockDim.x + threadIdx.x;
    if (n < N) deg[n] = 1;  // self-loop
    if (n == 0) rowptr[N] = E + N;
}

__global__ void k_deg_count(const int* __restrict__ ei, int* __restrict__ deg, int E) {
    int e = blockIdx.x * blockDim.x + threadIdx.x;
    if (e < E) atomicAdd(&deg[ei[E + e]], 1);  // dst
}

// 1024-thread single-block hierarchical scan (R2 verbatim)
__global__ void k_scan(const int* __restrict__ deg, int* __restrict__ rowptr,
                       int* __restrict__ cursor, int N) {
    __shared__ int wsum[16];
    __shared__ int wpre[16];
    int tid = threadIdx.x;
    int lane = tid & 63, wid = tid >> 6;
    int chunk = (N + 1023) >> 10;
    int beg = tid * chunk;
    int end = beg + chunk; if (end > N) end = N;
    int s = 0;
    for (int i = beg; i < end; i++) s += deg[i];
    int incl = s;
#pragma unroll
    for (int off = 1; off < 64; off <<= 1) {
        int v = __shfl_up(incl, off);
        if (lane >= off) incl += v;
    }
    if (lane == 63) wsum[wid] = incl;
    __syncthreads();
    if (tid == 0) {
        int r = 0;
        for (int i = 0; i < 16; i++) { wpre[i] = r; r += wsum[i]; }
    }
    __syncthreads();
    int run = wpre[wid] + incl - s;
    for (int i = beg; i < end; i++) {
        rowptr[i] = run;
        cursor[i] = run;
        run += deg[i];
    }
}

__global__ void k_scatter(const int* __restrict__ ei, int* __restrict__ cursor,
                          int* __restrict__ adj, int E, int N) {
    int i = blockIdx.x * blockDim.x + threadIdx.x;
    if (i >= E + N) return;
    int s, d;
    if (i < E) { s = ei[i]; d = ei[E + i]; }
    else { s = i - E; d = i - E; }      // self-loop
    int pos = atomicAdd(&cursor[d], 1);
    adj[pos] = s;
}

// ---------------- conv1 aggregate: 2 nodes per wave, single-pass online softmax (R2 verbatim) ----------------
__global__ void k_conv1(const int* __restrict__ rowptr, const int* __restrict__ adj,
                        const float* __restrict__ a_src, const float* __restrict__ a_dst,
                        const float* __restrict__ h1, const float* __restrict__ b1,
                        float* __restrict__ out1, int N) {
    int lane = threadIdx.x & 63;
    int wave = (blockIdx.x * blockDim.x + threadIdx.x) >> 6;
    int sub = lane & 31;           // channel 0..31
    int slot = lane >> 5;
    int hh = sub >> 4;
    int n = wave * 2 + slot;
    if (n >= N) return;
    int beg = rowptr[n], end = rowptr[n + 1];
    float ad = a_dst[n * 2 + hh];
    float m = -1e30f, denom = 0.f, acc = 0.f;
    for (int j0 = beg; j0 < end; j0 += 32) {
        int idx = j0 + sub;
        int av = (idx < end) ? adj[idx] : 0;
        int cnt = end - j0; if (cnt > 32) cnt = 32;
        for (int jj = 0; jj < cnt; jj++) {
            int s = __shfl(av, jj, 32);
            float t = a_src[s * 2 + hh] + ad;
            t = t > 0.f ? t : NEG_SLOPE * t;
            float mn = fmaxf(m, t);
            float scale = __expf(m - mn);
            float ex = __expf(t - mn);
            float hv = h1[s * 32 + sub];
            denom = denom * scale + ex;
            acc = acc * scale + ex * hv;
            m = mn;
        }
    }
    out1[n * 32 + sub] = fmaxf(acc / denom + b1[sub], 0.f);
}

// ---------------- node transform for conv2 (R2 verbatim) ----------------
__global__ void k_node2(const float* __restrict__ out1, const float* __restrict__ W2,
                        const float* __restrict__ as2, const float* __restrict__ ad2,
                        float* __restrict__ h2, float* __restrict__ a_src2,
                        float* __restrict__ a_dst2, int N) {
    int lane = threadIdx.x & 63;
    int n = (blockIdx.x * blockDim.x + threadIdx.x) >> 6;
    if (n >= N) return;
    float acc = 0.f;
#pragma unroll
    for (int k = 0; k < 32; k++) acc += out1[n * 32 + k] * W2[k * 64 + lane];
    h2[n * 64 + lane] = acc;
    float s = acc * as2[lane];
    float d = acc * ad2[lane];
#pragma unroll
    for (int off = 16; off >= 1; off >>= 1) {
        s += __shfl_xor(s, off);
        d += __shfl_xor(d, off);
    }
    if ((lane & 31) == 0) {
        a_src2[n * 2 + (lane >> 5)] = s;
        a_dst2[n * 2 + (lane >> 5)] = d;
    }
}

// ---------------- conv2 aggregate: 1 node per wave, single-pass online softmax (R2 verbatim) ----------------
__global__ void k_conv2(const int* __restrict__ rowptr, const int* __restrict__ adj,
                        const float* __restrict__ a_src, const float* __restrict__ a_dst,
                        const float* __restrict__ h2, const float* __restrict__ b2,
                        float* __restrict__ hfin, int N) {
    int lane = threadIdx.x & 63;
    int n = (blockIdx.x * blockDim.x + threadIdx.x) >> 6;
    if (n >= N) return;
    int hh = lane >> 5;
    int beg = rowptr[n], end = rowptr[n + 1];
    float ad = a_dst[n * 2 + hh];
    float m = -1e30f, denom = 0.f, acc = 0.f;
    for (int j0 = beg; j0 < end; j0 += 64) {
        int idx = j0 + lane;
        int av = (idx < end) ? adj[idx] : 0;
        int cnt = end - j0; if (cnt > 64) cnt = 64;
        for (int jj = 0; jj < cnt; jj++) {
            int s = __shfl(av, jj);
            float t = a_src[s * 2 + hh] + ad;
            t = t > 0.f ? t : NEG_SLOPE * t;
            float mn = fmaxf(m, t);
            float scale = __expf(m - mn);
            float ex = __expf(t - mn);
            float hv = h2[s * 64 + lane];
            denom = denom * scale + ex;
            acc = acc * scale + ex * hv;
            m = mn;
        }
    }
    hfin[n * 64 + lane] = fmaxf(acc / denom + b2[lane], 0.f);
}

// ---------------- per-node fc1: g = hfin @ fc1_w + 0.5*b1 ----------------
__global__ void k_fc1node(const float* __restrict__ hfin, const float* __restrict__ w1,
                          const float* __restrict__ b1, float* __restrict__ g, int N) {
    int lane = threadIdx.x & 63;
    int n = (blockIdx.x * blockDim.x + threadIdx.x) >> 6;
    if (n >= N) return;
    float hv = hfin[n * 64 + lane];
    float acc = 0.5f * b1[lane];
#pragma unroll
    for (int k = 0; k < 64; k++) acc += __shfl(hv, k) * w1[k * 64 + lane];
    g[n * 64 + lane] = acc;
}

// ---------------- edge head: out = relu(g[r]+g[c]) . w2 + b2 ----------------
__global__ void k_head2(const int* __restrict__ ei, const float* __restrict__ g,
                        const float* __restrict__ w2, const float* __restrict__ b2,
                        float* __restrict__ out, int E) {
    int e = blockIdx.x * blockDim.x + threadIdx.x;
    if (e >= E) return;
    int r = ei[e], c = ei[E + e];
    const float4* gr = (const float4*)(g + (size_t)r * 64);
    const float4* gc = (const float4*)(g + (size_t)c * 64);
    float o = b2[0];
#pragma unroll
    for (int t = 0; t < 16; t++) {
        float4 a = gr[t], b = gc[t];
        o += fmaxf(a.x + b.x, 0.f) * w2[4 * t + 0];
        o += fmaxf(a.y + b.y, 0.f) * w2[4 * t + 1];
        o += fmaxf(a.z + b.z, 0.f) * w2[4 * t + 2];
        o += fmaxf(a.w + b.w, 0.f) * w2[4 * t + 3];
    }
    out[e] = o;
}

extern "C" void kernel_launch(void* const* d_in, const int* in_sizes, int n_in,
                              void* d_out, int out_size, void* d_ws, size_t ws_size,
                              hipStream_t stream) {
    const float* x   = (const float*)d_in[0];
    const int*   ei  = (const int*)d_in[1];
    const float* W1  = (const float*)d_in[2];
    const float* as1 = (const float*)d_in[3];
    const float* ad1 = (const float*)d_in[4];
    const float* b1  = (const float*)d_in[5];
    const float* W2  = (const float*)d_in[6];
    const float* as2 = (const float*)d_in[7];
    const float* ad2 = (const float*)d_in[8];
    const float* b2  = (const float*)d_in[9];
    const float* fw1 = (const float*)d_in[10];
    const float* fb1 = (const float*)d_in[11];
    const float* fw2 = (const float*)d_in[12];
    const float* fb2 = (const float*)d_in[13];
    float* out = (float*)d_out;

    int N = in_sizes[0] / 8;
    int E = in_sizes[1] / 2;
    int M = E + N;

    // ---- workspace layout: EXACTLY R2's (known-good, 47.2MB), plus g
    //      overlaid on the dead [h1|asr1|adt1|out1-prefix] region (no growth).
    char* w = (char*)d_ws;
    float* h1    = (float*)w;              w += (size_t)N * 32 * 4;
    float* asr1  = (float*)w;              w += (size_t)N * 2 * 4;
    float* adt1  = (float*)w;              w += (size_t)N * 2 * 4;
    float* out1  = (float*)w;              w += (size_t)N * 32 * 4;
    float* h2    = (float*)w;              w += (size_t)N * 64 * 4;
    float* asr2  = (float*)w;              w += (size_t)N * 2 * 4;
    float* adt2  = (float*)w;              w += (size_t)N * 2 * 4;
    float* hfin  = (float*)w;              w += (size_t)N * 64 * 4;
    int*   deg   = (int*)w;                w += (size_t)N * 4;
    int*   rowp  = (int*)w;                w += (size_t)(N + 1) * 4;
    int*   curs  = (int*)w;                w += (size_t)N * 4;
    int*   adj   = (int*)w;                w += (size_t)M * 4;
    float* g     = h1;   // 64N floats over h1(32N)+asr1(2N)+adt1(2N)+out1[0,28N) — all dead post-conv2

    int B = 256;
    k_node1<<<(N + B - 1) / B, B, 0, stream>>>(x, W1, as1, ad1, h1, asr1, adt1, N);
    k_deg_init<<<(N + B - 1) / B, B, 0, stream>>>(deg, rowp, N, E);
    k_deg_count<<<(E + B - 1) / B, B, 0, stream>>>(ei, deg, E);
    k_scan<<<1, 1024, 0, stream>>>(deg, rowp, curs, N);
    k_scatter<<<(M + B - 1) / B, B, 0, stream>>>(ei, curs, adj, E, N);
    {
        long long thr = (long long)((N + 1) / 2) * 64;
        k_conv1<<<(int)((thr + B - 1) / B), B, 0, stream>>>(rowp, adj, asr1, adt1, h1, b1, out1, N);
    }
    {
        long long thr = (long long)N * 64;
        k_node2<<<(int)((thr + B - 1) / B), B, 0, stream>>>(out1, W2, as2, ad2, h2, asr2, adt2, N);
    }
    {
        long long thr = (long long)N * 64;
        k_conv2<<<(int)((thr + B - 1) / B), B, 0, stream>>>(rowp, adj, asr2, adt2, h2, b2, hfin, N);
    }
    {
        long long thr = (long long)N * 64;
        k_fc1node<<<(int)((thr + B - 1) / B), B, 0, stream>>>(hfin, fw1, fb1, g, N);
    }
    k_head2<<<(E + B - 1) / B, B, 0, stream>>>(ei, g, fw2, fb2, out, E);
}